// Round 8
// baseline (6787.322 us; speedup 1.0000x reference)
//
#include <hip/hip_runtime.h>
#include <stdint.h>

// Problem dims (fixed)
#define H_DIM   4096
#define FF_DIM  14336
#define M_TOK   8192     // B*S = 4*2048
#define KC1     (H_DIM / 32)    // 128 bf16 k-chunks for K=H (fallback)
#define KC2     (FF_DIM / 32)   // 448 bf16 k-chunks for K=FF
#define NC1     (H_DIM / 64)    // 64 i8 K-64 chunks for gemm1

typedef unsigned short ushort_t;
typedef __attribute__((ext_vector_type(8)))  short bf16x8;
typedef __attribute__((ext_vector_type(4)))  float f32x4;
typedef __attribute__((ext_vector_type(4)))  int   i32x4;

// ---------- scalar converters ----------
__device__ __forceinline__ unsigned short f2bf(float f) {
    union { float f; uint32_t u; } v; v.f = f;
    uint32_t r = v.u + 0x7FFFu + ((v.u >> 16) & 1u);
    return (unsigned short)(r >> 16);
}
__device__ __forceinline__ unsigned short t2bf(int v) {
    unsigned int mag = (v & 1) ? 0x3F80u : 0u;
    unsigned int sgn = ((unsigned int)v >> 16) & 0x8000u;
    return (unsigned short)(mag | sgn);
}
__device__ __forceinline__ bf16x8 pack_f8(f32x4 a, f32x4 b) {
    bf16x8 o;
    o[0]=(short)f2bf(a[0]); o[1]=(short)f2bf(a[1]); o[2]=(short)f2bf(a[2]); o[3]=(short)f2bf(a[3]);
    o[4]=(short)f2bf(b[0]); o[5]=(short)f2bf(b[1]); o[6]=(short)f2bf(b[2]); o[7]=(short)f2bf(b[3]);
    return o;
}
__device__ __forceinline__ bf16x8 pack_t8(i32x4 a, i32x4 b) {
    bf16x8 o;
    o[0]=(short)t2bf(a[0]); o[1]=(short)t2bf(a[1]); o[2]=(short)t2bf(a[2]); o[3]=(short)t2bf(a[3]);
    o[4]=(short)t2bf(b[0]); o[5]=(short)t2bf(b[1]); o[6]=(short)t2bf(b[2]); o[7]=(short)t2bf(b[3]);
    return o;
}
__device__ __forceinline__ int pack4(int a, int b, int c, int d) {
    return (a & 255) | ((b & 255) << 8) | ((c & 255) << 16) | ((d & 255) << 24);
}

#define GLDS16(gp, lp) __builtin_amdgcn_global_load_lds( \
    (__attribute__((address_space(1))) void*)(gp),       \
    (__attribute__((address_space(3))) void*)(lp), 16, 0, 0)

#define WAITVM8  asm volatile("s_waitcnt vmcnt(8)" ::: "memory")
#define WAITVM6  asm volatile("s_waitcnt vmcnt(6)" ::: "memory")
#define WAITVM4  asm volatile("s_waitcnt vmcnt(4)" ::: "memory")
#define WAITVM0  asm volatile("s_waitcnt vmcnt(0)" ::: "memory")
#define SBAR     asm volatile("s_barrier" ::: "memory")

// =====================================================================
// bf16 frag layout (16x16 frags), row-major [R][K]:
//   t=row/128, c=k/32, f=(row%128)/16, l=(row%16)+((k%32)/8)*16, e=k%8
//   flat = ((t*(K/32)+c)*8+f)*512 + l*8 + e     (8 KiB per (t,c))
// i8 frag layout (16x16 frags, K-chunks of 64):
//   t=row/128, c=k/64, f=(row%128)/16, l=(row%16)+16*((k%64)/16), j=k%16
//   byte = (t*(K/64)+c)*8192 + f*1024 + l*16 + j
//   k-internal order cancels (A/B packed with same bijection).
// =====================================================================

// ---------------- bf16 converter (LDS transpose, coalesced) ----------------
template<int K, bool TERN>
__global__ __launch_bounds__(256)
void k_cvt_lds(const void* __restrict__ inv, unsigned short* __restrict__ out) {
    constexpr int KC = K / 32;
    constexpr int CP = K / 64;
    __shared__ int sm[128][68];
    const int b   = blockIdx.x;
    const int t   = b / CP;
    const int cp  = b % CP;
    const int tid = threadIdx.x;
    const int rr  = tid >> 4;
    const int c4  = (tid & 15) * 4;
    const int k0  = cp * 64;

    const int* in = (const int*)inv;
    #pragma unroll
    for (int p = 0; p < 8; ++p) {
        const int row = p * 16 + rr;
        *(i32x4*)&sm[row][c4] = *(const i32x4*)(in + (size_t)(t * 128 + row) * K + k0 + c4);
    }
    __syncthreads();
    #pragma unroll
    for (int p = 0; p < 4; ++p) {
        const int idx = p * 256 + tid;
        const int cc  = idx >> 9;
        const int f   = (idx >> 6) & 7;
        const int l   = idx & 63;
        const int row = f * 16 + (l & 15);
        const int kl  = cc * 32 + (l >> 4) * 8;
        bf16x8 o;
        if (TERN) {
            i32x4 a = *(const i32x4*)&sm[row][kl];
            i32x4 bq = *(const i32x4*)&sm[row][kl + 4];
            o = pack_t8(a, bq);
        } else {
            f32x4 a = *(const f32x4*)&sm[row][kl];
            f32x4 bq = *(const f32x4*)&sm[row][kl + 4];
            o = pack_f8(a, bq);
        }
        *(bf16x8*)(out + (((size_t)t * KC + (cp * 2 + cc)) * 8 + f) * 512 + (size_t)l * 8) = o;
    }
}

// ---------------- per-token amax for x int8 quantization ----------------
__global__ __launch_bounds__(256)
void k_amax(const float* __restrict__ x, float* __restrict__ sx, float* __restrict__ rsx) {
    const int row  = blockIdx.x * 4 + (threadIdx.x >> 6);
    const int lane = threadIdx.x & 63;
    const f32x4* p = (const f32x4*)(x + (size_t)row * H_DIM);
    float m = 0.f;
    #pragma unroll 4
    for (int i = lane; i < H_DIM / 4; i += 64) {
        f32x4 v = p[i];
        m = fmaxf(m, fmaxf(fmaxf(fabsf(v[0]), fabsf(v[1])), fmaxf(fabsf(v[2]), fabsf(v[3]))));
    }
    #pragma unroll
    for (int o = 32; o; o >>= 1) m = fmaxf(m, __shfl_xor(m, o, 64));
    if (lane == 0) {
        sx[row]  = m * (1.f / 127.f);
        rsx[row] = m > 0.f ? 127.f / m : 0.f;
    }
}

// ---------------- i8 frag converter (16x16 frag layout) ----------------
// block: 128 rows x 64 k (one K-64 chunk)
template<int K, bool TERN>
__global__ __launch_bounds__(256)
void k_cvt_i8(const void* __restrict__ inv, const float* __restrict__ rsx,
              char* __restrict__ out) {
    constexpr int CP = K / 64;
    __shared__ int sm[128][68];
    const int b   = blockIdx.x;
    const int t   = b / CP;
    const int cp  = b % CP;
    const int tid = threadIdx.x;
    const int rr  = tid >> 4;
    const int c4  = (tid & 15) * 4;

    const int* in = (const int*)inv;
    #pragma unroll
    for (int p = 0; p < 8; ++p) {
        const int row = p * 16 + rr;
        *(i32x4*)&sm[row][c4] = *(const i32x4*)(in + (size_t)(t * 128 + row) * K + cp * 64 + c4);
    }
    __syncthreads();
    #pragma unroll
    for (int p = 0; p < 2; ++p) {
        const int pos = p * 256 + tid;          // 0..511
        const int f = pos >> 6, l = pos & 63;
        const int row = f * 16 + (l & 15);
        const int kb  = (l >> 4) * 16;
        i32x4 o;
        if constexpr (TERN) {
            #pragma unroll
            for (int q = 0; q < 4; ++q)
                o[q] = pack4(sm[row][kb + q * 4], sm[row][kb + q * 4 + 1],
                             sm[row][kb + q * 4 + 2], sm[row][kb + q * 4 + 3]);
        } else {
            const float rs = rsx[t * 128 + row];
            #pragma unroll
            for (int q = 0; q < 4; ++q) {
                const float* fp = (const float*)&sm[row][kb + q * 4];
                o[q] = pack4(__float2int_rn(fp[0] * rs), __float2int_rn(fp[1] * rs),
                             __float2int_rn(fp[2] * rs), __float2int_rn(fp[3] * rs));
            }
        }
        *(i32x4*)(out + ((size_t)t * CP + cp) * 8192 + f * 1024 + (size_t)l * 16) = o;
    }
}

// ------- GEMM1 i8 16x16x64, 256x256 tile: halved LDS-read bytes/output -------
// 8 waves as 2M x 4N; wave-tile 128M x 64N (x2 for gate+up). Per chunk:
// LDS reads = 8 x (A 8K + G 4K + U 4K) = 128 KB for a 256x256 tile
// (was 96 KB for 256x128 -> -33% LDS bytes per output; LDS-BW-bound kernel).
// LDS: 3 slots x 48 KB {A 16K | G 16K | U 16K}, depth-2, vmcnt(6).
// Stage issued AFTER trailing barrier (slot readers provably done).
__global__ __launch_bounds__(512, 2)
void k_gemm1_i8(const char* __restrict__ xq,
                const char* __restrict__ gq, const char* __restrict__ uq,
                const float* __restrict__ sxp,
                const float* __restrict__ gs, const float* __restrict__ us,
                ushort_t* __restrict__ hid)
{
    __shared__ char lds[147456];   // 3 slots x 48 KB
    const int tid  = threadIdx.x;
    const int lane = tid & 63;
    const int wv   = tid >> 6;
    const int wr   = wv >> 2;          // 0..1 (M: 128 rows each)
    const int wc   = wv & 3;           // 0..3 (N: 64 cols each)
    const int l15  = lane & 15;
    const int lq   = lane >> 4;

    const int bid = blockIdx.x;
    const int bmt = bid & 31;          // 32 m-tiles of 256 (M-fastest)
    const int bnt = bid >> 5;          // 56 ff-tiles of 256

    const char* xa0 = xq + (size_t)(bmt * 2)     * NC1 * 8192;
    const char* xa1 = xq + (size_t)(bmt * 2 + 1) * NC1 * 8192;
    const char* gb0 = gq + (size_t)(bnt * 2)     * NC1 * 8192;
    const char* gb1 = gq + (size_t)(bnt * 2 + 1) * NC1 * 8192;
    const char* ub0 = uq + (size_t)(bnt * 2)     * NC1 * 8192;
    const char* ub1 = uq + (size_t)(bnt * 2 + 1) * NC1 * 8192;

    i32x4 accg[8][4] = {};
    i32x4 accu[8][4] = {};

#define STG(h, s) { char* sl_ = lds + (s) * 49152;                            \
    GLDS16(xa0 + (size_t)(h) * 8192 + tid * 16, sl_ + tid * 16);              \
    GLDS16(xa1 + (size_t)(h) * 8192 + tid * 16, sl_ + 8192  + tid * 16);      \
    GLDS16(gb0 + (size_t)(h) * 8192 + tid * 16, sl_ + 16384 + tid * 16);      \
    GLDS16(gb1 + (size_t)(h) * 8192 + tid * 16, sl_ + 24576 + tid * 16);      \
    GLDS16(ub0 + (size_t)(h) * 8192 + tid * 16, sl_ + 32768 + tid * 16);      \
    GLDS16(ub1 + (size_t)(h) * 8192 + tid * 16, sl_ + 40960 + tid * 16); }

#define G1BODY(WAITOP, SLOT)                                                        \
  {                                                                                 \
    WAITOP;       /* own chunk-H loads done */                                      \
    SBAR;         /* all waves' chunk-H loads done */                               \
    char* slot = lds + (SLOT) * 49152;                                              \
    const char* Ab = slot + wr * 8192 + lane * 16;                                  \
    const char* Gb = slot + 16384 + (wc >> 1) * 8192 + ((wc & 1) * 4) * 1024 + lane * 16; \
    const char* Ub = Gb + 16384;                                                    \
    i32x4 af[8], gf[4], uf[4];                                                      \
    _Pragma("unroll")                                                               \
    for (int m = 0; m < 8; m++) af[m] = *(const i32x4*)(Ab + m * 1024);             \
    _Pragma("unroll")                                                               \
    for (int n = 0; n < 4; n++) {                                                   \
        gf[n] = *(const i32x4*)(Gb + n * 1024);                                     \
        uf[n] = *(const i32x4*)(Ub + n * 1024);                                     \
    }                                                                               \
    __builtin_amdgcn_s_setprio(1);                                                  \
    _Pragma("unroll")                                                               \
    for (int m = 0; m < 8; m++)                                                     \
      _Pragma("unroll")                                                             \
      for (int n = 0; n < 4; n++)                                                   \
        accg[m][n] = __builtin_amdgcn_mfma_i32_16x16x64_i8(af[m], gf[n], accg[m][n], 0, 0, 0); \
    _Pragma("unroll")                                                               \
    for (int m = 0; m < 8; m++)                                                     \
      _Pragma("unroll")                                                             \
      for (int n = 0; n < 4; n++)                                                   \
        accu[m][n] = __builtin_amdgcn_mfma_i32_16x16x64_i8(af[m], uf[n], accu[m][n], 0, 0, 0); \
    __builtin_amdgcn_s_setprio(0);                                                  \
    SBAR;         /* slot readers done before anyone re-stages it */                \
  }

    STG(0, 0); STG(1, 1);
    int s0 = 0;                         // slot of chunk H
    for (int H = 0; H < NC1 - 2; ++H) {
        const int sn = (s0 + 2 >= 3) ? s0 - 1 : s0 + 2;   // slot for H+2
        G1BODY(WAITVM6, s0);
        STG(H + 2, sn);
        s0 = (s0 + 1 >= 3) ? 0 : s0 + 1;
    }
    G1BODY(WAITVM6, s0);  s0 = (s0 + 1 >= 3) ? 0 : s0 + 1;   // H = NC1-2
    G1BODY(WAITVM0, s0);                                      // H = NC1-1
#undef G1BODY
#undef STG

    // epilogue: dequant (i32 * sx * scale), silu(g)*u, store bf16 hidden in frag order
    const int bm0 = bmt * 256;
    const int bn0 = bnt * 256;
    float sxv[8][4];
    #pragma unroll
    for (int m = 0; m < 8; m++) {
        const int rb = bm0 + wr * 128 + m * 16 + lq * 4;
        #pragma unroll
        for (int r = 0; r < 4; r++) sxv[m][r] = sxp[rb + r];
    }
    #pragma unroll
    for (int n = 0; n < 4; n++) {
        const int gcol = bn0 + wc * 64 + n * 16 + l15;   // k index for gemm2
        const float sg = gs[gcol];
        const float su = us[gcol];
        const int c  = gcol >> 5;
        const int lp = ((gcol & 31) >> 3) * 16;
        const int e  = gcol & 7;
        #pragma unroll
        for (int m = 0; m < 8; m++) {
            const int rb = bm0 + wr * 128 + m * 16 + lq * 4;
            #pragma unroll
            for (int r = 0; r < 4; r++) {
                const int row = rb + r;
                float g = (float)accg[m][n][r] * (sxv[m][r] * sg);
                float u = (float)accu[m][n][r] * (sxv[m][r] * su);
                float hv = g * (1.0f / (1.0f + __expf(-g))) * u;
                const int t = row >> 7;
                const int f = (row >> 4) & 7;
                const int l = (row & 15) + lp;
                hid[(((size_t)t * KC2 + c) * 8 + f) * 512 + l * 8 + e] = f2bf(hv);
            }
        }
    }
}

// ---------------- GEMM2 8-phase bf16: out = (hidden @ down^T) * ds ----------------
__global__ __launch_bounds__(512, 2)
void k_gemm2_8p(const ushort_t* __restrict__ hid, const ushort_t* __restrict__ db,
                const float* __restrict__ dsc, float* __restrict__ out)
{
    __shared__ ushort_t lds[65536];
    const int tid  = threadIdx.x;
    const int lane = tid & 63;
    const int wv   = tid >> 6;
    const int wr   = wv >> 2;
    const int wc   = wv & 3;
    const int l15  = lane & 15;
    const int lq   = lane >> 4;

    const int bid = blockIdx.x;
    const int bmt = bid & 31;
    const int bnt = bid >> 5;

    const ushort_t* ha0 = hid + ((size_t)(bmt * 2)     * KC2) * 4096;
    const ushort_t* ha1 = hid + ((size_t)(bmt * 2 + 1) * KC2) * 4096;
    const ushort_t* db0 = db  + ((size_t)(bnt * 2)     * KC2) * 4096;
    const ushort_t* db1 = db  + ((size_t)(bnt * 2 + 1) * KC2) * 4096;

    f32x4 acc[8][4] = {};

    #pragma unroll
    for (int h = 0; h < 3; ++h) {
        ushort_t* sl = lds + h * 16384;
        GLDS16(ha0 + (size_t)h * 4096 + tid * 8, sl + tid * 8);
        GLDS16(ha1 + (size_t)h * 4096 + tid * 8, sl + 4096 + tid * 8);
        GLDS16(db0 + (size_t)h * 4096 + tid * 8, sl + 8192 + tid * 8);
        GLDS16(db1 + (size_t)h * 4096 + tid * 8, sl + 12288 + tid * 8);
    }

#define G2_HALF(WAITOP, DO_ISSUE)                                                  \
  {                                                                                \
    ushort_t* slot = lds + (H & 3) * 16384;                                        \
    const ushort_t* Ab = slot + wr * 4096 + lane * 8;                              \
    const ushort_t* Bb = slot + 8192 + (wc >> 1) * 4096 + ((wc & 1) * 4) * 512 + lane * 8; \
    WAITOP;                                                                        \
    SBAR;                                                                          \
    bf16x8 af[4], bfv[4];                                                          \
    _Pragma("unroll")                                                              \
    for (int m = 0; m < 4; m++) af[m] = *(const bf16x8*)(Ab + m * 512);            \
    _Pragma("unroll")                                                              \
    for (int n = 0; n < 4; n++) bfv[n] = *(const bf16x8*)(Bb + n * 512);           \
    if (DO_ISSUE) {                                                                \
      const int Hp = H + 3;                                                        \
      ushort_t* sp = lds + (Hp & 3) * 16384;                                       \
      GLDS16(ha0 + (size_t)Hp * 4096 + tid * 8, sp + tid * 8);                     \
      GLDS16(ha1 + (size_t)Hp * 4096 + tid * 8, sp + 4096 + tid * 8);              \
    }                                                                              \
    __builtin_amdgcn_s_setprio(1);                                                 \
    _Pragma("unroll")                                                              \
    for (int m = 0; m < 4; m++)                                                    \
      _Pragma("unroll")                                                            \
      for (int n = 0; n < 4; n++)                                                  \
        acc[m][n] = __builtin_amdgcn_mfma_f32_16x16x32_bf16(af[m], bfv[n], acc[m][n], 0, 0, 0); \
    __builtin_amdgcn_s_setprio(0);                                                 \
    SBAR;                                                                          \
    bf16x8 af2[4];                                                                 \
    _Pragma("unroll")                                                              \
    for (int m = 0; m < 4; m++) af2[m] = *(const bf16x8*)(Ab + (4 + m) * 512);     \
    if (DO_ISSUE) {                                                                \
      const int Hp = H + 3;                                                        \
      ushort_t* sp = lds + (Hp & 3) * 16384;                                       \
      GLDS16(db0 + (size_t)Hp * 4096 + tid * 8, sp + 8192 + tid * 8);              \
      GLDS16(db1 + (size_t)Hp * 4096 + tid * 8, sp + 12288 + tid * 8);             \
    }                                                                              \
    __builtin_amdgcn_s_setprio(1);                                                 \
    _Pragma("unroll")                                                              \
    for (int m = 0; m < 4; m++)                                                    \
      _Pragma("unroll")                                                            \
      for (int n = 0; n < 4; n++)                                                  \
        acc[4 + m][n] = __builtin_amdgcn_mfma_f32_16x16x32_bf16(af2[m], bfv[n], acc[4 + m][n], 0, 0, 0); \
    __builtin_amdgcn_s_setprio(0);                                                 \
  }

    int H = 0;
    for (; H < KC2 - 3; ++H) G2_HALF(WAITVM8, 1);
    G2_HALF(WAITVM8, 0); ++H;
    G2_HALF(WAITVM4, 0); ++H;
    G2_HALF(WAITVM0, 0);
#undef G2_HALF

    const int bm0 = bmt * 256;
    const int bn0 = bnt * 256;
    #pragma unroll
    for (int n = 0; n < 4; n++) {
        const int gcol = bn0 + wc * 64 + n * 16 + l15;
        const float sd = dsc[gcol];
        #pragma unroll
        for (int m = 0; m < 8; m++) {
            const int grow = bm0 + wr * 128 + m * 16 + lq * 4;
            #pragma unroll
            for (int r = 0; r < 4; r++)
                out[(size_t)(grow + r) * H_DIM + gcol] = acc[m][n][r] * sd;
        }
    }
}

// ================= fallback (small ws) — R2 structure, known good =================
__device__ __forceinline__ void ds_write_frag(ushort_t* buf, int crow, int ccol,
                                              bf16x8 lo, bf16x8 hi) {
    int f  = crow >> 4;
    int la = (crow & 15) + (((ccol)     & 31) >> 3) * 16;
    int lb = (crow & 15) + (((ccol + 8) & 31) >> 3) * 16;
    *(bf16x8*)&buf[f * 512 + la * 8] = lo;
    *(bf16x8*)&buf[f * 512 + lb * 8] = hi;
}

template<bool PREA>
__global__ __launch_bounds__(256, 2)
void k_gemm1_fb(const float* __restrict__ xf, const ushort_t* __restrict__ xb,
                const int* __restrict__ gt, const int* __restrict__ ut,
                const float* __restrict__ gs, const float* __restrict__ us,
                ushort_t* __restrict__ hid)
{
    __shared__ ushort_t As[4096];
    __shared__ ushort_t Gs[4096];
    __shared__ ushort_t Us[4096];

    const int tid  = threadIdx.x;
    const int lane = tid & 63;
    const int wv   = tid >> 6;
    const int wr   = wv >> 1;
    const int wc   = wv & 1;
    const int l15  = lane & 15;
    const int lq   = lane >> 4;

    const int bid = blockIdx.x;
    const int bmt = bid & 63;
    const int bnt = bid >> 6;
    const int bm0 = bmt * 128;
    const int bn0 = bnt * 128;

    f32x4 accg[4][4] = {};
    f32x4 accu[4][4] = {};

    const ushort_t* pa = PREA ? xb + (size_t)bmt * KC1 * 4096 : nullptr;
    const int crow = tid >> 1;
    const int ccol = (tid & 1) * 16;

    for (int kc = 0; kc < KC1; kc++) {
        __syncthreads();
        const int k0 = kc * 32;
        if constexpr (PREA) {
            GLDS16(pa + tid * 8,        &As[tid * 8]);
            GLDS16(pa + tid * 8 + 2048, &As[tid * 8 + 2048]);
        } else {
            const float* xa = xf + (size_t)(bm0 + crow) * H_DIM + k0 + ccol;
            f32x4 a0 = ((const f32x4*)xa)[0], a1 = ((const f32x4*)xa)[1];
            f32x4 a2 = ((const f32x4*)xa)[2], a3 = ((const f32x4*)xa)[3];
            ds_write_frag(As, crow, ccol, pack_f8(a0, a1), pack_f8(a2, a3));
        }
        {
            const size_t wo = (size_t)(bn0 + crow) * H_DIM + k0 + ccol;
            const i32x4* gp = (const i32x4*)(gt + wo);
            i32x4 g0 = gp[0], g1 = gp[1], g2 = gp[2], g3 = gp[3];
            ds_write_frag(Gs, crow, ccol, pack_t8(g0, g1), pack_t8(g2, g3));
            const i32x4* up = (const i32x4*)(ut + wo);
            i32x4 u0 = up[0], u1 = up[1], u2 = up[2], u3 = up[3];
            ds_write_frag(Us, crow, ccol, pack_t8(u0, u1), pack_t8(u2, u3));
        }
        __syncthreads();

        bf16x8 af[4], gf[4], uf[4];
        #pragma unroll
        for (int m = 0; m < 4; m++)
            af[m] = *(const bf16x8*)&As[(wr * 4 + m) * 512 + lane * 8];
        #pragma unroll
        for (int n = 0; n < 4; n++) {
            gf[n] = *(const bf16x8*)&Gs[(wc * 4 + n) * 512 + lane * 8];
            uf[n] = *(const bf16x8*)&Us[(wc * 4 + n) * 512 + lane * 8];
        }
        #pragma unroll
        for (int m = 0; m < 4; m++)
            #pragma unroll
            for (int n = 0; n < 4; n++) {
                accg[m][n] = __builtin_amdgcn_mfma_f32_16x16x32_bf16(af[m], gf[n], accg[m][n], 0, 0, 0);
                accu[m][n] = __builtin_amdgcn_mfma_f32_16x16x32_bf16(af[m], uf[n], accu[m][n], 0, 0, 0);
            }
        if constexpr (PREA) pa += 4096;
    }

    #pragma unroll
    for (int n = 0; n < 4; n++) {
        const int gcol = bn0 + wc * 64 + n * 16 + l15;
        const float sg = gs[gcol];
        const float su = us[gcol];
        const int c  = gcol >> 5;
        const int lp = ((gcol & 31) >> 3) * 16;
        const int e  = gcol & 7;
        #pragma unroll
        for (int m = 0; m < 4; m++) {
            const int rb = bm0 + wr * 64 + m * 16 + lq * 4;
            #pragma unroll
            for (int r = 0; r < 4; r++) {
                const int row = rb + r;
                float g = accg[m][n][r] * sg;
                float u = accu[m][n][r] * su;
                float hv = g * (1.0f / (1.0f + __expf(-g))) * u;
                const int t = row >> 7;
                const int f = (row >> 4) & 7;
                const int l = (row & 15) + lp;
                hid[(((size_t)t * KC2 + c) * 8 + f) * 512 + l * 8 + e] = f2bf(hv);
            }
        }
    }
}

__global__ __launch_bounds__(256, 2)
void k_gemm2_fb(const ushort_t* __restrict__ hid, const int* __restrict__ dt,
                const float* __restrict__ dsc, float* __restrict__ out)
{
    __shared__ ushort_t As[4096];
    __shared__ ushort_t Bs[4096];

    const int tid  = threadIdx.x;
    const int lane = tid & 63;
    const int wv   = tid >> 6;
    const int wr   = wv >> 1;
    const int wc   = wv & 1;
    const int l15  = lane & 15;
    const int lq   = lane >> 4;

    const int bid = blockIdx.x;
    const int bmt = bid & 63;
    const int bnt = bid >> 6;
    const int bm0 = bmt * 128;
    const int bn0 = bnt * 128;

    f32x4 acc[4][4] = {};
    const ushort_t* pa = hid + (size_t)bmt * KC2 * 4096;
    const int crow = tid >> 1;
    const int ccol = (tid & 1) * 16;

    for (int kc = 0; kc < KC2; kc++) {
        __syncthreads();
        GLDS16(pa + tid * 8,        &As[tid * 8]);
        GLDS16(pa + tid * 8 + 2048, &As[tid * 8 + 2048]);
        {
            const i32x4* dp = (const i32x4*)(dt + (size_t)(bn0 + crow) * FF_DIM + kc * 32 + ccol);
            i32x4 d0 = dp[0], d1 = dp[1], d2 = dp[2], d3 = dp[3];
            ds_write_frag(Bs, crow, ccol, pack_t8(d0, d1), pack_t8(d2, d3));
        }
        __syncthreads();

        bf16x8 af[4], bfr[4];
        #pragma unroll
        for (int m = 0; m < 4; m++)
            af[m] = *(const bf16x8*)&As[(wr * 4 + m) * 512 + lane * 8];
        #pragma unroll
        for (int n = 0; n < 4; n++)
            bfr[n] = *(const bf16x8*)&Bs[(wc * 4 + n) * 512 + lane * 8];
        #pragma unroll
        for (int m = 0; m < 4; m++)
            #pragma unroll
            for (int n = 0; n < 4; n++)
                acc[m][n] = __builtin_amdgcn_mfma_f32_16x16x32_bf16(af[m], bfr[n], acc[m][n], 0, 0, 0);
        pa += 4096;
    }

    #pragma unroll
    for (int n = 0; n < 4; n++) {
        const int gcol = bn0 + wc * 64 + n * 16 + l15;
        const float sd = dsc[gcol];
        #pragma unroll
        for (int m = 0; m < 4; m++) {
            const int grow = bm0 + wr * 64 + m * 16 + lq * 4;
            #pragma unroll
            for (int r = 0; r < 4; r++)
                out[(size_t)(grow + r) * H_DIM + gcol] = acc[m][n][r] * sd;
        }
    }
}

extern "C" void kernel_launch(void* const* d_in, const int* in_sizes, int n_in,
                              void* d_out, int out_size, void* d_ws, size_t ws_size,
                              hipStream_t stream) {
    const float* xf  = (const float*)d_in[0];
    const int*   gt  = (const int*)d_in[1];
    const int*   ut  = (const int*)d_in[2];
    const int*   dt  = (const int*)d_in[3];
    const float* gsc = (const float*)d_in[4];
    const float* usc = (const float*)d_in[5];
    const float* dsc = (const float*)d_in[6];
    float* out = (float*)d_out;

    const size_t HID_B = (size_t)M_TOK * FF_DIM * 2;   // 224 MiB hidden bf16 frag
    const size_t DB_B  = (size_t)FF_DIM * H_DIM * 2;   // 112 MiB down bf16 frag
    const size_t G8_B  = (size_t)FF_DIM * H_DIM;       // 56 MiB gate i8 frag
    const size_t U8_B  = (size_t)FF_DIM * H_DIM;       // 56 MiB up i8 frag
    const size_t X8_B  = (size_t)M_TOK * H_DIM;        // 32 MiB x i8 frag
    const size_t SX_B  = (size_t)M_TOK * 4;            // 32 KiB
    const size_t XB_B  = (size_t)M_TOK * H_DIM * 2;    // 64 MiB x bf16 frag (fallback)

    char* base = (char*)d_ws;
    ushort_t* hid = (ushort_t*)base;
    ushort_t* dbp = (ushort_t*)(base + HID_B);
    char*     g8  = base + HID_B + DB_B;
    char*     u8  = g8 + G8_B;
    char*     x8  = u8 + U8_B;
    float*    sxp = (float*)(x8 + X8_B);
    float*    rsx = sxp + M_TOK;
    ushort_t* xbp = (ushort_t*)(base + HID_B);         // fallback only (excl. with dbp)

    const bool has_w  = ws_size >= HID_B + DB_B + G8_B + U8_B + X8_B + 2 * SX_B;
    const bool has_xb = ws_size >= HID_B + XB_B;

    if (has_w) {
        k_amax<<<M_TOK / 4, 256, 0, stream>>>(xf, sxp, rsx);
        k_cvt_i8<H_DIM,  false><<<(M_TOK / 128) * (H_DIM / 64), 256, 0, stream>>>(xf, rsx, x8);
        k_cvt_i8<H_DIM,  true ><<<(FF_DIM / 128) * (H_DIM / 64), 256, 0, stream>>>(gt, nullptr, g8);
        k_cvt_i8<H_DIM,  true ><<<(FF_DIM / 128) * (H_DIM / 64), 256, 0, stream>>>(ut, nullptr, u8);
        k_cvt_lds<FF_DIM, true><<<(H_DIM / 128) * (FF_DIM / 64), 256, 0, stream>>>(dt, dbp);

        k_gemm1_i8<<<32 * 56, 512, 0, stream>>>(x8, g8, u8, sxp, gsc, usc, hid);
        k_gemm2_8p<<<32 * 16, 512, 0, stream>>>(hid, dbp, dsc, out);
    } else {
        const int grid1 = 64 * 112;
        const int grid2 = 64 * 32;
        if (has_xb) {
            k_cvt_lds<H_DIM, false><<<(M_TOK / 128) * (H_DIM / 64), 256, 0, stream>>>(xf, xbp);
            k_gemm1_fb<true><<<grid1, 256, 0, stream>>>(nullptr, xbp, gt, ut, gsc, usc, hid);
        } else {
            k_gemm1_fb<false><<<grid1, 256, 0, stream>>>(xf, nullptr, gt, ut, gsc, usc, hid);
        }
        k_gemm2_fb<<<grid2, 256, 0, stream>>>(hid, dt, dsc, out);
    }
}

// Round 9
// 1725.484 us; speedup vs baseline: 3.9336x; 3.9336x over previous
//
#include <hip/hip_runtime.h>
#include <stdint.h>

// Problem dims (fixed)
#define H_DIM   4096
#define FF_DIM  14336
#define M_TOK   8192     // B*S = 4*2048
#define KC1     (H_DIM / 32)    // 128 bf16 k-chunks for K=H (fallback)
#define KC2     (FF_DIM / 32)   // 448 bf16 k-chunks for K=FF
#define KC1_8   (H_DIM / 64)    // 64 i8 K-64 chunks for gemm1

typedef unsigned short ushort_t;
typedef __attribute__((ext_vector_type(8)))  short bf16x8;
typedef __attribute__((ext_vector_type(4)))  float f32x4;
typedef __attribute__((ext_vector_type(4)))  int   i32x4;

// ---------- scalar converters ----------
__device__ __forceinline__ unsigned short f2bf(float f) {
    union { float f; uint32_t u; } v; v.f = f;
    uint32_t r = v.u + 0x7FFFu + ((v.u >> 16) & 1u);
    return (unsigned short)(r >> 16);
}
__device__ __forceinline__ unsigned short t2bf(int v) {
    unsigned int mag = (v & 1) ? 0x3F80u : 0u;
    unsigned int sgn = ((unsigned int)v >> 16) & 0x8000u;
    return (unsigned short)(mag | sgn);
}
__device__ __forceinline__ bf16x8 pack_f8(f32x4 a, f32x4 b) {
    bf16x8 o;
    o[0]=(short)f2bf(a[0]); o[1]=(short)f2bf(a[1]); o[2]=(short)f2bf(a[2]); o[3]=(short)f2bf(a[3]);
    o[4]=(short)f2bf(b[0]); o[5]=(short)f2bf(b[1]); o[6]=(short)f2bf(b[2]); o[7]=(short)f2bf(b[3]);
    return o;
}
__device__ __forceinline__ bf16x8 pack_t8(i32x4 a, i32x4 b) {
    bf16x8 o;
    o[0]=(short)t2bf(a[0]); o[1]=(short)t2bf(a[1]); o[2]=(short)t2bf(a[2]); o[3]=(short)t2bf(a[3]);
    o[4]=(short)t2bf(b[0]); o[5]=(short)t2bf(b[1]); o[6]=(short)t2bf(b[2]); o[7]=(short)t2bf(b[3]);
    return o;
}
__device__ __forceinline__ int pack4(int a, int b, int c, int d) {
    return (a & 255) | ((b & 255) << 8) | ((c & 255) << 16) | ((d & 255) << 24);
}

#define GLDS16(gp, lp) __builtin_amdgcn_global_load_lds( \
    (__attribute__((address_space(1))) void*)(gp),       \
    (__attribute__((address_space(3))) void*)(lp), 16, 0, 0)

#define WAITVM8  asm volatile("s_waitcnt vmcnt(8)" ::: "memory")
#define WAITVM4  asm volatile("s_waitcnt vmcnt(4)" ::: "memory")
#define WAITVM0  asm volatile("s_waitcnt vmcnt(0)" ::: "memory")
#define SBAR     asm volatile("s_barrier" ::: "memory")

// =====================================================================
// bf16 frag layout (16x16 frags), row-major [R][K]:
//   t=row/128, c=k/32, f=(row%128)/16, l=(row%16)+((k%32)/8)*16, e=k%8
//   flat = ((t*(K/32)+c)*8+f)*512 + l*8 + e     (8 KiB per (t,c))
// i8 frag layout (16x16 frags, K-chunks of 64):
//   t=row/128, c=k/64, f=(row%128)/16, l=(row%16)+16*((k%64)/16), j=k%16
//   byte = (t*(K/64)+c)*8192 + f*1024 + l*16 + j
//   k-internal order cancels (A/B packed with same bijection).
// =====================================================================

// ---------------- bf16 converter (LDS transpose, coalesced) ----------------
template<int K, bool TERN>
__global__ __launch_bounds__(256)
void k_cvt_lds(const void* __restrict__ inv, unsigned short* __restrict__ out) {
    constexpr int KC = K / 32;
    constexpr int CP = K / 64;
    __shared__ int sm[128][68];
    const int b   = blockIdx.x;
    const int t   = b / CP;
    const int cp  = b % CP;
    const int tid = threadIdx.x;
    const int rr  = tid >> 4;
    const int c4  = (tid & 15) * 4;
    const int k0  = cp * 64;

    const int* in = (const int*)inv;
    #pragma unroll
    for (int p = 0; p < 8; ++p) {
        const int row = p * 16 + rr;
        *(i32x4*)&sm[row][c4] = *(const i32x4*)(in + (size_t)(t * 128 + row) * K + k0 + c4);
    }
    __syncthreads();
    #pragma unroll
    for (int p = 0; p < 4; ++p) {
        const int idx = p * 256 + tid;
        const int cc  = idx >> 9;
        const int f   = (idx >> 6) & 7;
        const int l   = idx & 63;
        const int row = f * 16 + (l & 15);
        const int kl  = cc * 32 + (l >> 4) * 8;
        bf16x8 o;
        if (TERN) {
            i32x4 a = *(const i32x4*)&sm[row][kl];
            i32x4 bq = *(const i32x4*)&sm[row][kl + 4];
            o = pack_t8(a, bq);
        } else {
            f32x4 a = *(const f32x4*)&sm[row][kl];
            f32x4 bq = *(const f32x4*)&sm[row][kl + 4];
            o = pack_f8(a, bq);
        }
        *(bf16x8*)(out + (((size_t)t * KC + (cp * 2 + cc)) * 8 + f) * 512 + (size_t)l * 8) = o;
    }
}

// ---------------- per-token amax for x int8 quantization ----------------
__global__ __launch_bounds__(256)
void k_amax(const float* __restrict__ x, float* __restrict__ sx, float* __restrict__ rsx) {
    const int row  = blockIdx.x * 4 + (threadIdx.x >> 6);
    const int lane = threadIdx.x & 63;
    const f32x4* p = (const f32x4*)(x + (size_t)row * H_DIM);
    float m = 0.f;
    #pragma unroll 4
    for (int i = lane; i < H_DIM / 4; i += 64) {
        f32x4 v = p[i];
        m = fmaxf(m, fmaxf(fmaxf(fabsf(v[0]), fabsf(v[1])), fmaxf(fabsf(v[2]), fabsf(v[3]))));
    }
    #pragma unroll
    for (int o = 32; o; o >>= 1) m = fmaxf(m, __shfl_xor(m, o, 64));
    if (lane == 0) {
        sx[row]  = m * (1.f / 127.f);
        rsx[row] = m > 0.f ? 127.f / m : 0.f;
    }
}

// ---------------- i8 frag converter (16x16 frag layout) ----------------
// block: 128 rows x 64 k (one K-64 chunk)
template<int K, bool TERN>
__global__ __launch_bounds__(256)
void k_cvt_i8(const void* __restrict__ inv, const float* __restrict__ rsx,
              char* __restrict__ out) {
    constexpr int CP = K / 64;
    __shared__ int sm[128][68];
    const int b   = blockIdx.x;
    const int t   = b / CP;
    const int cp  = b % CP;
    const int tid = threadIdx.x;
    const int rr  = tid >> 4;
    const int c4  = (tid & 15) * 4;

    const int* in = (const int*)inv;
    #pragma unroll
    for (int p = 0; p < 8; ++p) {
        const int row = p * 16 + rr;
        *(i32x4*)&sm[row][c4] = *(const i32x4*)(in + (size_t)(t * 128 + row) * K + cp * 64 + c4);
    }
    __syncthreads();
    #pragma unroll
    for (int p = 0; p < 2; ++p) {
        const int pos = p * 256 + tid;          // 0..511
        const int f = pos >> 6, l = pos & 63;
        const int row = f * 16 + (l & 15);
        const int kb  = (l >> 4) * 16;
        i32x4 o;
        if constexpr (TERN) {
            #pragma unroll
            for (int q = 0; q < 4; ++q)
                o[q] = pack4(sm[row][kb + q * 4], sm[row][kb + q * 4 + 1],
                             sm[row][kb + q * 4 + 2], sm[row][kb + q * 4 + 3]);
        } else {
            const float rs = rsx[t * 128 + row];
            #pragma unroll
            for (int q = 0; q < 4; ++q) {
                const float* fp = (const float*)&sm[row][kb + q * 4];
                o[q] = pack4(__float2int_rn(fp[0] * rs), __float2int_rn(fp[1] * rs),
                             __float2int_rn(fp[2] * rs), __float2int_rn(fp[3] * rs));
            }
        }
        *(i32x4*)(out + ((size_t)t * CP + cp) * 8192 + f * 1024 + (size_t)l * 16) = o;
    }
}

// ---------------- GEMM1 int8 8-phase (R4 best: 857 us) ----------------
// 256M x (128 gate + 128 up) tile, 8 waves (4Mx2N), K-chunks of 64.
// LDS: 4 slots x 32KB (A0 8K, A1 8K, G 8K, U 8K). Depth-3 prefetch, vmcnt(8).
__global__ __launch_bounds__(512, 2)
void k_gemm1_i8(const char* __restrict__ xq,
                const char* __restrict__ gq, const char* __restrict__ uq,
                const float* __restrict__ sxp,
                const float* __restrict__ gs, const float* __restrict__ us,
                ushort_t* __restrict__ hid)
{
    __shared__ char lds[131072];   // 128 KiB
    const int tid  = threadIdx.x;
    const int lane = tid & 63;
    const int wv   = tid >> 6;
    const int wr   = wv >> 1;          // 0..3 (M)
    const int wc   = wv & 1;           // 0..1 (N)
    const int l15  = lane & 15;
    const int lq   = lane >> 4;

    const int bid = blockIdx.x;
    const int bmt = bid & 31;          // 32 m-tiles of 256 (M-fastest)
    const int bnt = bid >> 5;          // 112 ff-tiles of 128

    const char* xa0 = xq + (size_t)(bmt * 2)     * KC1_8 * 8192;
    const char* xa1 = xq + (size_t)(bmt * 2 + 1) * KC1_8 * 8192;
    const char* gbb = gq + (size_t)bnt * KC1_8 * 8192;
    const char* ubb = uq + (size_t)bnt * KC1_8 * 8192;

    i32x4 accg[4][4] = {};
    i32x4 accu[4][4] = {};

    // prologue: stage chunks 0,1,2
    #pragma unroll
    for (int h = 0; h < 3; ++h) {
        char* sl = lds + h * 32768;
        GLDS16(xa0 + (size_t)h * 8192 + tid * 16, sl + tid * 16);
        GLDS16(xa1 + (size_t)h * 8192 + tid * 16, sl + 8192 + tid * 16);
        GLDS16(gbb + (size_t)h * 8192 + tid * 16, sl + 16384 + tid * 16);
        GLDS16(ubb + (size_t)h * 8192 + tid * 16, sl + 24576 + tid * 16);
    }

#define G1I(WAITOP, DO_ISSUE)                                                      \
  {                                                                                \
    char* slot = lds + (H & 3) * 32768;                                            \
    const char* Ab = slot + (wr >> 1) * 8192 + ((wr & 1) * 4) * 1024 + lane * 16;  \
    const char* Gb = slot + 16384 + (wc * 4) * 1024 + lane * 16;                   \
    const char* Ub = slot + 24576 + (wc * 4) * 1024 + lane * 16;                   \
    WAITOP;                                                                        \
    SBAR;                                                                          \
    i32x4 af[4], gf[4], uf[4];                                                     \
    _Pragma("unroll")                                                              \
    for (int m = 0; m < 4; m++) af[m] = *(const i32x4*)(Ab + m * 1024);            \
    _Pragma("unroll")                                                              \
    for (int n = 0; n < 4; n++) gf[n] = *(const i32x4*)(Gb + n * 1024);            \
    if (DO_ISSUE) {                                                                \
      const int Hp = H + 3;                                                        \
      char* sp = lds + (Hp & 3) * 32768;                                           \
      GLDS16(xa0 + (size_t)Hp * 8192 + tid * 16, sp + tid * 16);                   \
      GLDS16(xa1 + (size_t)Hp * 8192 + tid * 16, sp + 8192 + tid * 16);            \
    }                                                                              \
    __builtin_amdgcn_s_setprio(1);                                                 \
    _Pragma("unroll")                                                              \
    for (int m = 0; m < 4; m++)                                                    \
      _Pragma("unroll")                                                            \
      for (int n = 0; n < 4; n++)                                                  \
        accg[m][n] = __builtin_amdgcn_mfma_i32_16x16x64_i8(af[m], gf[n], accg[m][n], 0, 0, 0); \
    __builtin_amdgcn_s_setprio(0);                                                 \
    SBAR;                                                                          \
    _Pragma("unroll")                                                              \
    for (int n = 0; n < 4; n++) uf[n] = *(const i32x4*)(Ub + n * 1024);            \
    if (DO_ISSUE) {                                                                \
      const int Hp = H + 3;                                                        \
      char* sp = lds + (Hp & 3) * 32768;                                           \
      GLDS16(gbb + (size_t)Hp * 8192 + tid * 16, sp + 16384 + tid * 16);           \
      GLDS16(ubb + (size_t)Hp * 8192 + tid * 16, sp + 24576 + tid * 16);           \
    }                                                                              \
    __builtin_amdgcn_s_setprio(1);                                                 \
    _Pragma("unroll")                                                              \
    for (int m = 0; m < 4; m++)                                                    \
      _Pragma("unroll")                                                            \
      for (int n = 0; n < 4; n++)                                                  \
        accu[m][n] = __builtin_amdgcn_mfma_i32_16x16x64_i8(af[m], uf[n], accu[m][n], 0, 0, 0); \
    __builtin_amdgcn_s_setprio(0);                                                 \
  }

    int H = 0;
    for (; H < KC1_8 - 3; ++H) G1I(WAITVM8, 1);
    G1I(WAITVM8, 0); ++H;
    G1I(WAITVM4, 0); ++H;
    G1I(WAITVM0, 0);
#undef G1I

    // epilogue: dequant (i32 * sx * scale), silu(g)*u, store bf16 hidden in frag order
    const int bm0 = bmt * 256;
    const int bn0 = bnt * 128;
    float sxv[4][4];
    #pragma unroll
    for (int m = 0; m < 4; m++) {
        const int rb = bm0 + wr * 64 + m * 16 + lq * 4;
        #pragma unroll
        for (int r = 0; r < 4; r++) sxv[m][r] = sxp[rb + r];
    }
    #pragma unroll
    for (int n = 0; n < 4; n++) {
        const int gcol = bn0 + wc * 64 + n * 16 + l15;   // k index for gemm2
        const float sg = gs[gcol];
        const float su = us[gcol];
        const int c  = gcol >> 5;
        const int lp = ((gcol & 31) >> 3) * 16;
        const int e  = gcol & 7;
        #pragma unroll
        for (int m = 0; m < 4; m++) {
            const int rb = bm0 + wr * 64 + m * 16 + lq * 4;
            #pragma unroll
            for (int r = 0; r < 4; r++) {
                const int row = rb + r;
                float g = (float)accg[m][n][r] * (sxv[m][r] * sg);
                float u = (float)accu[m][n][r] * (sxv[m][r] * su);
                float hv = g * (1.0f / (1.0f + __expf(-g))) * u;
                const int t = row >> 7;
                const int f = (row >> 4) & 7;
                const int l = (row & 15) + lp;
                hid[(((size_t)t * KC2 + c) * 8 + f) * 512 + l * 8 + e] = f2bf(hv);
            }
        }
    }
}

// ---------------- GEMM2 8-phase bf16: out = (hidden @ down^T) * ds ----------------
__global__ __launch_bounds__(512, 2)
void k_gemm2_8p(const ushort_t* __restrict__ hid, const ushort_t* __restrict__ db,
                const float* __restrict__ dsc, float* __restrict__ out)
{
    __shared__ ushort_t lds[65536];
    const int tid  = threadIdx.x;
    const int lane = tid & 63;
    const int wv   = tid >> 6;
    const int wr   = wv >> 2;
    const int wc   = wv & 3;
    const int l15  = lane & 15;
    const int lq   = lane >> 4;

    const int bid = blockIdx.x;
    const int bmt = bid & 31;
    const int bnt = bid >> 5;

    const ushort_t* ha0 = hid + ((size_t)(bmt * 2)     * KC2) * 4096;
    const ushort_t* ha1 = hid + ((size_t)(bmt * 2 + 1) * KC2) * 4096;
    const ushort_t* db0 = db  + ((size_t)(bnt * 2)     * KC2) * 4096;
    const ushort_t* db1 = db  + ((size_t)(bnt * 2 + 1) * KC2) * 4096;

    f32x4 acc[8][4] = {};

    #pragma unroll
    for (int h = 0; h < 3; ++h) {
        ushort_t* sl = lds + h * 16384;
        GLDS16(ha0 + (size_t)h * 4096 + tid * 8, sl + tid * 8);
        GLDS16(ha1 + (size_t)h * 4096 + tid * 8, sl + 4096 + tid * 8);
        GLDS16(db0 + (size_t)h * 4096 + tid * 8, sl + 8192 + tid * 8);
        GLDS16(db1 + (size_t)h * 4096 + tid * 8, sl + 12288 + tid * 8);
    }

#define G2_HALF(WAITOP, DO_ISSUE)                                                  \
  {                                                                                \
    ushort_t* slot = lds + (H & 3) * 16384;                                        \
    const ushort_t* Ab = slot + wr * 4096 + lane * 8;                              \
    const ushort_t* Bb = slot + 8192 + (wc >> 1) * 4096 + ((wc & 1) * 4) * 512 + lane * 8; \
    WAITOP;                                                                        \
    SBAR;                                                                          \
    bf16x8 af[4], bfv[4];                                                          \
    _Pragma("unroll")                                                              \
    for (int m = 0; m < 4; m++) af[m] = *(const bf16x8*)(Ab + m * 512);            \
    _Pragma("unroll")                                                              \
    for (int n = 0; n < 4; n++) bfv[n] = *(const bf16x8*)(Bb + n * 512);           \
    if (DO_ISSUE) {                                                                \
      const int Hp = H + 3;                                                        \
      ushort_t* sp = lds + (Hp & 3) * 16384;                                       \
      GLDS16(ha0 + (size_t)Hp * 4096 + tid * 8, sp + tid * 8);                     \
      GLDS16(ha1 + (size_t)Hp * 4096 + tid * 8, sp + 4096 + tid * 8);              \
    }                                                                              \
    __builtin_amdgcn_s_setprio(1);                                                 \
    _Pragma("unroll")                                                              \
    for (int m = 0; m < 4; m++)                                                    \
      _Pragma("unroll")                                                            \
      for (int n = 0; n < 4; n++)                                                  \
        acc[m][n] = __builtin_amdgcn_mfma_f32_16x16x32_bf16(af[m], bfv[n], acc[m][n], 0, 0, 0); \
    __builtin_amdgcn_s_setprio(0);                                                 \
    SBAR;                                                                          \
    bf16x8 af2[4];                                                                 \
    _Pragma("unroll")                                                              \
    for (int m = 0; m < 4; m++) af2[m] = *(const bf16x8*)(Ab + (4 + m) * 512);     \
    if (DO_ISSUE) {                                                                \
      const int Hp = H + 3;                                                        \
      ushort_t* sp = lds + (Hp & 3) * 16384;                                       \
      GLDS16(db0 + (size_t)Hp * 4096 + tid * 8, sp + 8192 + tid * 8);              \
      GLDS16(db1 + (size_t)Hp * 4096 + tid * 8, sp + 12288 + tid * 8);             \
    }                                                                              \
    __builtin_amdgcn_s_setprio(1);                                                 \
    _Pragma("unroll")                                                              \
    for (int m = 0; m < 4; m++)                                                    \
      _Pragma("unroll")                                                            \
      for (int n = 0; n < 4; n++)                                                  \
        acc[4 + m][n] = __builtin_amdgcn_mfma_f32_16x16x32_bf16(af2[m], bfv[n], acc[4 + m][n], 0, 0, 0); \
    __builtin_amdgcn_s_setprio(0);                                                 \
  }

    int H = 0;
    for (; H < KC2 - 3; ++H) G2_HALF(WAITVM8, 1);
    G2_HALF(WAITVM8, 0); ++H;
    G2_HALF(WAITVM4, 0); ++H;
    G2_HALF(WAITVM0, 0);
#undef G2_HALF

    const int bm0 = bmt * 256;
    const int bn0 = bnt * 256;
    #pragma unroll
    for (int n = 0; n < 4; n++) {
        const int gcol = bn0 + wc * 64 + n * 16 + l15;
        const float sd = dsc[gcol];
        #pragma unroll
        for (int m = 0; m < 8; m++) {
            const int grow = bm0 + wr * 128 + m * 16 + lq * 4;
            #pragma unroll
            for (int r = 0; r < 4; r++)
                out[(size_t)(grow + r) * H_DIM + gcol] = acc[m][n][r] * sd;
        }
    }
}

// ================= fallback (small ws) — R2 structure, known good =================
__device__ __forceinline__ void ds_write_frag(ushort_t* buf, int crow, int ccol,
                                              bf16x8 lo, bf16x8 hi) {
    int f  = crow >> 4;
    int la = (crow & 15) + (((ccol)     & 31) >> 3) * 16;
    int lb = (crow & 15) + (((ccol + 8) & 31) >> 3) * 16;
    *(bf16x8*)&buf[f * 512 + la * 8] = lo;
    *(bf16x8*)&buf[f * 512 + lb * 8] = hi;
}

template<bool PREA>
__global__ __launch_bounds__(256, 2)
void k_gemm1_fb(const float* __restrict__ xf, const ushort_t* __restrict__ xb,
                const int* __restrict__ gt, const int* __restrict__ ut,
                const float* __restrict__ gs, const float* __restrict__ us,
                ushort_t* __restrict__ hid)
{
    __shared__ ushort_t As[4096];
    __shared__ ushort_t Gs[4096];
    __shared__ ushort_t Us[4096];

    const int tid  = threadIdx.x;
    const int lane = tid & 63;
    const int wv   = tid >> 6;
    const int wr   = wv >> 1;
    const int wc   = wv & 1;
    const int l15  = lane & 15;
    const int lq   = lane >> 4;

    const int bid = blockIdx.x;
    const int bmt = bid & 63;
    const int bnt = bid >> 6;
    const int bm0 = bmt * 128;
    const int bn0 = bnt * 128;

    f32x4 accg[4][4] = {};
    f32x4 accu[4][4] = {};

    const ushort_t* pa = PREA ? xb + (size_t)bmt * KC1 * 4096 : nullptr;
    const int crow = tid >> 1;
    const int ccol = (tid & 1) * 16;

    for (int kc = 0; kc < KC1; kc++) {
        __syncthreads();
        const int k0 = kc * 32;
        if constexpr (PREA) {
            GLDS16(pa + tid * 8,        &As[tid * 8]);
            GLDS16(pa + tid * 8 + 2048, &As[tid * 8 + 2048]);
        } else {
            const float* xa = xf + (size_t)(bm0 + crow) * H_DIM + k0 + ccol;
            f32x4 a0 = ((const f32x4*)xa)[0], a1 = ((const f32x4*)xa)[1];
            f32x4 a2 = ((const f32x4*)xa)[2], a3 = ((const f32x4*)xa)[3];
            ds_write_frag(As, crow, ccol, pack_f8(a0, a1), pack_f8(a2, a3));
        }
        {
            const size_t wo = (size_t)(bn0 + crow) * H_DIM + k0 + ccol;
            const i32x4* gp = (const i32x4*)(gt + wo);
            i32x4 g0 = gp[0], g1 = gp[1], g2 = gp[2], g3 = gp[3];
            ds_write_frag(Gs, crow, ccol, pack_t8(g0, g1), pack_t8(g2, g3));
            const i32x4* up = (const i32x4*)(ut + wo);
            i32x4 u0 = up[0], u1 = up[1], u2 = up[2], u3 = up[3];
            ds_write_frag(Us, crow, ccol, pack_t8(u0, u1), pack_t8(u2, u3));
        }
        __syncthreads();

        bf16x8 af[4], gf[4], uf[4];
        #pragma unroll
        for (int m = 0; m < 4; m++)
            af[m] = *(const bf16x8*)&As[(wr * 4 + m) * 512 + lane * 8];
        #pragma unroll
        for (int n = 0; n < 4; n++) {
            gf[n] = *(const bf16x8*)&Gs[(wc * 4 + n) * 512 + lane * 8];
            uf[n] = *(const bf16x8*)&Us[(wc * 4 + n) * 512 + lane * 8];
        }
        #pragma unroll
        for (int m = 0; m < 4; m++)
            #pragma unroll
            for (int n = 0; n < 4; n++) {
                accg[m][n] = __builtin_amdgcn_mfma_f32_16x16x32_bf16(af[m], gf[n], accg[m][n], 0, 0, 0);
                accu[m][n] = __builtin_amdgcn_mfma_f32_16x16x32_bf16(af[m], uf[n], accu[m][n], 0, 0, 0);
            }
        if constexpr (PREA) pa += 4096;
    }

    #pragma unroll
    for (int n = 0; n < 4; n++) {
        const int gcol = bn0 + wc * 64 + n * 16 + l15;
        const float sg = gs[gcol];
        const float su = us[gcol];
        const int c  = gcol >> 5;
        const int lp = ((gcol & 31) >> 3) * 16;
        const int e  = gcol & 7;
        #pragma unroll
        for (int m = 0; m < 4; m++) {
            const int rb = bm0 + wr * 64 + m * 16 + lq * 4;
            #pragma unroll
            for (int r = 0; r < 4; r++) {
                const int row = rb + r;
                float g = accg[m][n][r] * sg;
                float u = accu[m][n][r] * su;
                float hv = g * (1.0f / (1.0f + __expf(-g))) * u;
                const int t = row >> 7;
                const int f = (row >> 4) & 7;
                const int l = (row & 15) + lp;
                hid[(((size_t)t * KC2 + c) * 8 + f) * 512 + l * 8 + e] = f2bf(hv);
            }
        }
    }
}

__global__ __launch_bounds__(256, 2)
void k_gemm2_fb(const ushort_t* __restrict__ hid, const int* __restrict__ dt,
                const float* __restrict__ dsc, float* __restrict__ out)
{
    __shared__ ushort_t As[4096];
    __shared__ ushort_t Bs[4096];

    const int tid  = threadIdx.x;
    const int lane = tid & 63;
    const int wv   = tid >> 6;
    const int wr   = wv >> 1;
    const int wc   = wv & 1;
    const int l15  = lane & 15;
    const int lq   = lane >> 4;

    const int bid = blockIdx.x;
    const int bmt = bid & 63;
    const int bnt = bid >> 6;
    const int bm0 = bmt * 128;
    const int bn0 = bnt * 128;

    f32x4 acc[4][4] = {};
    const ushort_t* pa = hid + (size_t)bmt * KC2 * 4096;
    const int crow = tid >> 1;
    const int ccol = (tid & 1) * 16;

    for (int kc = 0; kc < KC2; kc++) {
        __syncthreads();
        GLDS16(pa + tid * 8,        &As[tid * 8]);
        GLDS16(pa + tid * 8 + 2048, &As[tid * 8 + 2048]);
        {
            const i32x4* dp = (const i32x4*)(dt + (size_t)(bn0 + crow) * FF_DIM + kc * 32 + ccol);
            i32x4 d0 = dp[0], d1 = dp[1], d2 = dp[2], d3 = dp[3];
            ds_write_frag(Bs, crow, ccol, pack_t8(d0, d1), pack_t8(d2, d3));
        }
        __syncthreads();

        bf16x8 af[4], bfr[4];
        #pragma unroll
        for (int m = 0; m < 4; m++)
            af[m] = *(const bf16x8*)&As[(wr * 4 + m) * 512 + lane * 8];
        #pragma unroll
        for (int n = 0; n < 4; n++)
            bfr[n] = *(const bf16x8*)&Bs[(wc * 4 + n) * 512 + lane * 8];
        #pragma unroll
        for (int m = 0; m < 4; m++)
            #pragma unroll
            for (int n = 0; n < 4; n++)
                acc[m][n] = __builtin_amdgcn_mfma_f32_16x16x32_bf16(af[m], bfr[n], acc[m][n], 0, 0, 0);
        pa += 4096;
    }

    #pragma unroll
    for (int n = 0; n < 4; n++) {
        const int gcol = bn0 + wc * 64 + n * 16 + l15;
        const float sd = dsc[gcol];
        #pragma unroll
        for (int m = 0; m < 4; m++) {
            const int grow = bm0 + wr * 64 + m * 16 + lq * 4;
            #pragma unroll
            for (int r = 0; r < 4; r++)
                out[(size_t)(grow + r) * H_DIM + gcol] = acc[m][n][r] * sd;
        }
    }
}

extern "C" void kernel_launch(void* const* d_in, const int* in_sizes, int n_in,
                              void* d_out, int out_size, void* d_ws, size_t ws_size,
                              hipStream_t stream) {
    const float* xf  = (const float*)d_in[0];
    const int*   gt  = (const int*)d_in[1];
    const int*   ut  = (const int*)d_in[2];
    const int*   dt  = (const int*)d_in[3];
    const float* gsc = (const float*)d_in[4];
    const float* usc = (const float*)d_in[5];
    const float* dsc = (const float*)d_in[6];
    float* out = (float*)d_out;

    const size_t HID_B = (size_t)M_TOK * FF_DIM * 2;   // 224 MiB hidden bf16 frag
    const size_t DB_B  = (size_t)FF_DIM * H_DIM * 2;   // 112 MiB down bf16 frag
    const size_t G8_B  = (size_t)FF_DIM * H_DIM;       // 56 MiB gate i8 frag
    const size_t U8_B  = (size_t)FF_DIM * H_DIM;       // 56 MiB up i8 frag
    const size_t X8_B  = (size_t)M_TOK * H_DIM;        // 32 MiB x i8 frag
    const size_t SX_B  = (size_t)M_TOK * 4;            // 32 KiB
    const size_t XB_B  = (size_t)M_TOK * H_DIM * 2;    // 64 MiB x bf16 frag (fallback)

    char* base = (char*)d_ws;
    ushort_t* hid = (ushort_t*)base;
    ushort_t* dbp = (ushort_t*)(base + HID_B);
    char*     g8  = base + HID_B + DB_B;
    char*     u8  = g8 + G8_B;
    char*     x8  = u8 + U8_B;
    float*    sxp = (float*)(x8 + X8_B);
    float*    rsx = sxp + M_TOK;
    ushort_t* xbp = (ushort_t*)(base + HID_B);         // fallback only (excl. with dbp)

    const bool has_w  = ws_size >= HID_B + DB_B + G8_B + U8_B + X8_B + 2 * SX_B;
    const bool has_xb = ws_size >= HID_B + XB_B;

    if (has_w) {
        k_amax<<<M_TOK / 4, 256, 0, stream>>>(xf, sxp, rsx);
        k_cvt_i8<H_DIM,  false><<<(M_TOK / 128) * (H_DIM / 64), 256, 0, stream>>>(xf, rsx, x8);
        k_cvt_i8<H_DIM,  true ><<<(FF_DIM / 128) * (H_DIM / 64), 256, 0, stream>>>(gt, nullptr, g8);
        k_cvt_i8<H_DIM,  true ><<<(FF_DIM / 128) * (H_DIM / 64), 256, 0, stream>>>(ut, nullptr, u8);
        k_cvt_lds<FF_DIM, true><<<(H_DIM / 128) * (FF_DIM / 64), 256, 0, stream>>>(dt, dbp);

        k_gemm1_i8<<<32 * 112, 512, 0, stream>>>(x8, g8, u8, sxp, gsc, usc, hid);
        k_gemm2_8p<<<32 * 16, 512, 0, stream>>>(hid, dbp, dsc, out);
    } else {
        const int grid1 = 64 * 112;
        const int grid2 = 64 * 32;
        if (has_xb) {
            k_cvt_lds<H_DIM, false><<<(M_TOK / 128) * (H_DIM / 64), 256, 0, stream>>>(xf, xbp);
            k_gemm1_fb<true><<<grid1, 256, 0, stream>>>(nullptr, xbp, gt, ut, gsc, usc, hid);
        } else {
            k_gemm1_fb<false><<<grid1, 256, 0, stream>>>(xf, nullptr, gt, ut, gsc, usc, hid);
        }
        k_gemm2_fb<<<grid2, 256, 0, stream>>>(hid, dt, dsc, out);
    }
}